// Round 12
// baseline (3360.401 us; speedup 1.0000x reference)
//
#include <hip/hip_runtime.h>
#include <hip/hip_bf16.h>

// Problem constants (BLoraLinear): T=8192, D_IN=4096, D_OUT=4096, R=16, M=2, S=8
#define T_TOK 8192
#define DIN   4096
#define DOUT  4096
#define RANK  16
#define NMOD  2
#define NSEG  8

typedef __attribute__((ext_vector_type(8))) short bf16x8;
typedef __attribute__((ext_vector_type(8))) unsigned short u16x8;
typedef __attribute__((ext_vector_type(4))) float f32x4;

__device__ inline unsigned short f2bf(float f) {
    union { float f; unsigned u; } v; v.f = f;
    unsigned r = v.u + 0x7FFFu + ((v.u >> 16) & 1u);   // RNE
    return (unsigned short)(r >> 16);
}

__device__ inline void gload_lds16(const void* g, void* l) {
    __builtin_amdgcn_global_load_lds(
        (const __attribute__((address_space(1))) void*)g,
        (__attribute__((address_space(3))) void*)l, 16, 0, 0);
}

// ---------------- fp32 -> bf16 cast for x and W in one launch ----------------
__global__ void cast2_bf16_kernel(const float* __restrict__ sa,
                                  unsigned short* __restrict__ da, int n8a,
                                  const float* __restrict__ sb,
                                  unsigned short* __restrict__ db, int n8b) {
    int i = blockIdx.x * blockDim.x + threadIdx.x;
    const float* s;
    unsigned short* d;
    size_t j;
    if (i < n8a) { s = sa; d = da; j = (size_t)i; }
    else if (i < n8a + n8b) { s = sb; d = db; j = (size_t)(i - n8a); }
    else return;
    const float4* s4 = (const float4*)s;
    float4 a = s4[2 * j];
    float4 b = s4[2 * j + 1];
    u16x8 o;
    o[0] = f2bf(a.x); o[1] = f2bf(a.y); o[2] = f2bf(a.z); o[3] = f2bf(a.w);
    o[4] = f2bf(b.x); o[5] = f2bf(b.y); o[6] = f2bf(b.z); o[7] = f2bf(b.w);
    *(u16x8*)(d + 8 * j) = o;
}

// ---------- At[s][m*16+r][d] = lora_A[m][s][d][r]  (bf16) --------------------
__global__ void prep_A_kernel(const float* __restrict__ A,
                              unsigned short* __restrict__ At) {
    int idx = blockIdx.x * 256 + threadIdx.x;     // NSEG*32*DIN total
    int d   = idx & (DIN - 1);
    int smr = idx >> 12;
    int s   = smr >> 5, mr = smr & 31;
    int m   = mr >> 4,  r  = mr & 15;
    float v = A[(((size_t)(m * NSEG + s) * DIN) + d) * RANK + r];
    At[idx] = f2bf(v);
}

// ---------- Bt[s][o][m*16+r] = lora_B[m][s][r][o]  (bf16) --------------------
__global__ void prep_B_kernel(const float* __restrict__ B,
                              unsigned short* __restrict__ Bt) {
    int o  = blockIdx.x * 256 + threadIdx.x;      // NSEG*DOUT total
    int s  = o >> 12;
    int oc = o & (DOUT - 1);
    unsigned short tmp[32];
    for (int m = 0; m < NMOD; ++m)
        for (int r = 0; r < RANK; ++r)
            tmp[m * 16 + r] =
                f2bf(B[(((size_t)(m * NSEG + s) * RANK) + r) * DOUT + oc]);
    for (int k = 0; k < 4; ++k) {
        u16x8 v;
        for (int j = 0; j < 8; ++j) v[j] = tmp[k * 8 + j];
        *(u16x8*)(Bt + (size_t)o * 32 + k * 8) = v;
    }
}

// ---------- u partials: Pu[ky][t][mr] = sum_{k in split} x[t,k]*At[s(t)][mr][k]
__global__ __launch_bounds__(64) void u_gemm_kernel(
    const unsigned short* __restrict__ xb, const unsigned short* __restrict__ At,
    const int* __restrict__ cu, float* __restrict__ Pu) {
    int tile = blockIdx.x;          // 0..255
    int ky   = blockIdx.y;          // 0..3
    int lane = threadIdx.x;
    int l15  = lane & 15, lk = lane >> 4;
    int t0   = tile * 32;
    f32x4 acc[2][2] = {};
    bf16x8 zero = {};
    for (int s = 0; s < NSEG; ++s) {
        int lo = cu[s], hi = cu[s + 1];
        if (hi <= t0 || lo >= t0 + 32) continue;
        const unsigned short* atb = At + (size_t)(s * 32) * DIN;
        for (int kt = 0; kt < 32; ++kt) {
            int k0 = ky * 1024 + kt * 32 + lk * 8;
            bf16x8 a[2], b[2];
            for (int mi = 0; mi < 2; ++mi) {
                int row = t0 + mi * 16 + l15;
                bf16x8 av = *(const bf16x8*)(xb + (size_t)row * DIN + k0);
                a[mi] = (row >= lo && row < hi) ? av : zero;
            }
            for (int ni = 0; ni < 2; ++ni) {
                int mr = ni * 16 + l15;
                b[ni] = *(const bf16x8*)(atb + (size_t)mr * DIN + k0);
            }
            for (int mi = 0; mi < 2; ++mi)
                for (int ni = 0; ni < 2; ++ni)
                    acc[mi][ni] = __builtin_amdgcn_mfma_f32_16x16x32_bf16(
                        a[mi], b[ni], acc[mi][ni], 0, 0, 0);
        }
    }
    for (int mi = 0; mi < 2; ++mi)
        for (int ni = 0; ni < 2; ++ni)
            for (int j = 0; j < 4; ++j) {
                int t  = t0 + mi * 16 + lk * 4 + j;
                int mr = ni * 16 + l15;
                Pu[((size_t)ky * T_TOK + t) * 32 + mr] = acc[mi][ni][j];
            }
}

// ---------- reduce 4 K-split partials -> ub bf16 [T][32] ---------------------
__global__ void reduce_u_kernel(const float* __restrict__ Pu,
                                unsigned short* __restrict__ ub) {
    int idx = blockIdx.x * 256 + threadIdx.x;   // T_TOK*32
    const size_t STRIDE = (size_t)T_TOK * 32;
    float s = Pu[idx] + Pu[idx + STRIDE] + Pu[idx + 2 * STRIDE] + Pu[idx + 3 * STRIDE];
    ub[idx] = f2bf(s);
}

// ============================================================================
// Main GEMM — 2-blocks/CU with 256x256 tile. BK=32, 8 waves (2Mx4N), LDS 64KiB
// double-buffer (A[256][32]+B[256][32] = 32 KiB/slot) -> 2 blocks x 512 thr
// co-resident (VGPR<=128 = 16 waves/CU). ONE barrier per K-tile:
//   { ds_read 12 frags(t, slot s) ; stage 4 gloads (t+1 -> slot s^1) ;
//     setprio(1) 32 MFMA setprio(0) ; vmcnt(0) ; s_barrier }
// R12 fix vs R11: BODY(126) now has STG_=1 (stage distance is t+1, so the
// second-to-last body must stage the last tile; R11 left tile 127 unstaged ->
// absmax 1.07).
// dbuf audit: iter t reads slot t&1; stages into slot (t&1)^1, whose readers
// (tile t-1) completed before end-of-(t-1) barrier (compiler lgkm waits bind
// all 12 reads before that body's MFMAs). vmcnt(0)+barrier at end of t makes
// tile t+1 visible to every wave. vmcnt(0) drain is cheap: stage->use
// distance ~1 K-tile (~2300 cyc) >> 900-cyc HBM latency.
// Swizzle (64B rows, verified 0-conflict R9/R10): slot16 ^= (row>>1)&3 on
// SOURCE of global_load_lds (linear dest) and on ds_read address.
// XCD col-panel mapping: xcd=bid&7 owns col-panels {2*xcd, 2*xcd+1}; W slice
// 2 MiB at a time -> L2-resident; x shared across XCDs via L3.
// ============================================================================

__device__ __forceinline__ bf16x8 fragA(const char* mat, int row, int lk) {
    int rb = (row << 6) + ((lk ^ ((row >> 1) & 3)) << 4);
    return *(const bf16x8*)(mat + rb);
}

// stage 8 KiB round (512 threads x 16 B): rows TB>>6, pre-swizzled source
#define STAGE_R(GB_, LD_, TB_, K0_)                                           \
  { int tb = (TB_);                                                            \
    int lrow = tb >> 6;                                                        \
    int cb = (tb & 63) ^ (((lrow >> 1) & 3) << 4);                             \
    gload_lds16((GB_) + (size_t)lrow * DIN + (K0_) + (cb >> 1), (LD_) + tb); }

#define BODY(T_, S_, STG_, VM_, BAR_)                                          \
  {                                                                            \
    const char* cA = lds + (S_) * 32768;                                       \
    const char* cB = cA + 16384;                                               \
    char* sA = lds + (1 - (S_)) * 32768;                                       \
    char* sB = sA + 16384;                                                     \
    const int k0n = ((T_) + 1) * 32;                                           \
    bf16x8 af[8], bf[4];                                                       \
    for (int n = 0; n < 4; ++n) bf[n] = fragA(cB, wcol + n*16 + l15, lk);      \
    for (int m = 0; m < 8; ++m) af[m] = fragA(cA, wrow + m*16 + l15, lk);      \
    if (STG_) {                                                                \
        STAGE_R(xrow, sA, tid*16, k0n);                                        \
        STAGE_R(xrow, sA, 8192 + tid*16, k0n);                                 \
        STAGE_R(wrow_g, sB, tid*16, k0n);                                      \
        STAGE_R(wrow_g, sB, 8192 + tid*16, k0n);                               \
    }                                                                          \
    __builtin_amdgcn_s_setprio(1);                                             \
    for (int m = 0; m < 8; ++m)                                                \
        for (int n = 0; n < 4; ++n)                                            \
            acc[m][n] = __builtin_amdgcn_mfma_f32_16x16x32_bf16(               \
                af[m], bf[n], acc[m][n], 0, 0, 0);                             \
    __builtin_amdgcn_s_setprio(0);                                             \
    if ((VM_) >= 0) asm volatile("s_waitcnt vmcnt(0)" ::: "memory");           \
    if (BAR_) __builtin_amdgcn_s_barrier();                                    \
  }

__global__ __launch_bounds__(512, 4) void main_gemm_kernel(
    const unsigned short* __restrict__ xb, const unsigned short* __restrict__ wb,
    const unsigned short* __restrict__ ub, const unsigned short* __restrict__ bt,
    const float* __restrict__ bias, const int* __restrict__ cu,
    float* __restrict__ out) {
    __shared__ __attribute__((aligned(1024))) char lds[65536];  // 2 x 32 KiB
    int tid  = threadIdx.x;
    int w    = tid >> 6, lane = tid & 63;
    int l15  = lane & 15, lk = lane >> 4;
    int wrow = (w >> 2) * 128;          // wave M-offset in tile
    int wcol = (w & 3) * 64;            // wave N-offset in tile
    // XCD col-panel mapping: xcd owns col-panels {2*xcd, 2*xcd+1}
    int xcd   = blockIdx.x & 7;
    int local = blockIdx.x >> 3;        // 0..63
    int colp  = xcd * 2 + (local >> 5); // 0..15
    int rowp  = local & 31;             // 0..31
    int row0 = rowp * 256, col0 = colp * 256;

    const unsigned short* xrow   = xb + (size_t)row0 * DIN;
    const unsigned short* wrow_g = wb + (size_t)col0 * DIN;

    f32x4 acc[8][4] = {};

    // prologue: stage tile 0 into slot 0
    STAGE_R(xrow, lds, tid*16, 0);
    STAGE_R(xrow, lds, 8192 + tid*16, 0);
    STAGE_R(wrow_g, lds + 16384, tid*16, 0);
    STAGE_R(wrow_g, lds + 16384, 8192 + tid*16, 0);
    asm volatile("s_waitcnt vmcnt(0)" ::: "memory");
    __builtin_amdgcn_s_barrier();

    // main loop: 128 K-tiles of 32; unroll x2 for static dbuf slots
    #pragma unroll 1
    for (int t = 0; t < 126; t += 2) {
        BODY(t,     0, 1, 0, 1);
        BODY(t + 1, 1, 1, 0, 1);
    }
    BODY(126, 0, 1, 0, 1);   // stages tile 127 (stage distance = 1!)
    BODY(127, 1, 0, -1, 0);

    // fused LoRA up-projection: one extra K=32 MFMA step per overlapping segment
    bf16x8 zero = {};
    for (int s = 0; s < NSEG; ++s) {
        int lo = cu[s], hi = cu[s + 1];
        if (hi <= row0 || lo >= row0 + 256) continue;
        bf16x8 au[8], bu[4];
        for (int m = 0; m < 8; ++m) {
            int row = row0 + wrow + m * 16 + l15;
            bf16x8 v = *(const bf16x8*)(ub + (size_t)row * 32 + lk * 8);
            au[m] = (row >= lo && row < hi) ? v : zero;
        }
        for (int n = 0; n < 4; ++n) {
            int col = col0 + wcol + n * 16 + l15;
            bu[n] = *(const bf16x8*)(bt + ((size_t)s * DOUT + col) * 32 + lk * 8);
        }
        for (int m = 0; m < 8; ++m)
            for (int n = 0; n < 4; ++n)
                acc[m][n] = __builtin_amdgcn_mfma_f32_16x16x32_bf16(
                    au[m], bu[n], acc[m][n], 0, 0, 0);
    }

    // epilogue: + bias, fp32 store
    float bv[4];
    for (int n = 0; n < 4; ++n) bv[n] = bias[col0 + wcol + n * 16 + l15];
    for (int m = 0; m < 8; ++m) {
        int rbase = row0 + wrow + m * 16 + lk * 4;
        for (int n = 0; n < 4; ++n) {
            int col = col0 + wcol + n * 16 + l15;
            for (int jj = 0; jj < 4; ++jj)
                out[(size_t)(rbase + jj) * DOUT + col] = acc[m][n][jj] + bv[n];
        }
    }
}

extern "C" void kernel_launch(void* const* d_in, const int* in_sizes, int n_in,
                              void* d_out, int out_size, void* d_ws, size_t ws_size,
                              hipStream_t stream) {
    const float* x  = (const float*)d_in[0];
    const float* W  = (const float*)d_in[1];
    const float* b  = (const float*)d_in[2];
    const float* lA = (const float*)d_in[3];
    const float* lB = (const float*)d_in[4];
    const int*   cu = (const int*)d_in[5];
    float* out = (float*)d_out;

    char* ws = (char*)d_ws;
    unsigned short* xb = (unsigned short*)(ws);                    // 64 MiB
    unsigned short* wb = (unsigned short*)(ws + 67108864);         // 32 MiB
    unsigned short* At = (unsigned short*)(ws + 100663296);        // 2 MiB
    unsigned short* Bt = (unsigned short*)(ws + 102760448);        // 2 MiB
    float*          Pu = (float*)(ws + 104857600);                 // 4 MiB
    unsigned short* ub = (unsigned short*)(ws + 109051904);        // 0.5 MiB

    const int n8x = T_TOK * DIN / 8, n8w = DOUT * DIN / 8;
    cast2_bf16_kernel<<<(n8x + n8w) / 256, 256, 0, stream>>>(x, xb, n8x, W, wb, n8w);
    prep_A_kernel<<<(NSEG * 32 * DIN) / 256, 256, 0, stream>>>(lA, At);
    prep_B_kernel<<<(NSEG * DOUT) / 256, 256, 0, stream>>>(lB, Bt);
    dim3 ug(T_TOK / 32, 4);
    u_gemm_kernel<<<ug, 64, 0, stream>>>(xb, At, cu, Pu);
    reduce_u_kernel<<<(T_TOK * 32) / 256, 256, 0, stream>>>(Pu, ub);
    dim3 mg(32 * 16);   // 512 tiles of 256x256
    main_gemm_kernel<<<mg, 512, 0, stream>>>(xb, wb, ub, Bt, b, cu, out);
}

// Round 13
// 347.968 us; speedup vs baseline: 9.6572x; 9.6572x over previous
//
#include <hip/hip_runtime.h>
#include <hip/hip_bf16.h>

// Problem constants (BLoraLinear): T=8192, D_IN=4096, D_OUT=4096, R=16, M=2, S=8
#define T_TOK 8192
#define DIN   4096
#define DOUT  4096
#define RANK  16
#define NMOD  2
#define NSEG  8

typedef __attribute__((ext_vector_type(8))) short bf16x8;
typedef __attribute__((ext_vector_type(8))) unsigned short u16x8;
typedef __attribute__((ext_vector_type(4))) float f32x4;

__device__ inline unsigned short f2bf(float f) {
    union { float f; unsigned u; } v; v.f = f;
    unsigned r = v.u + 0x7FFFu + ((v.u >> 16) & 1u);   // RNE
    return (unsigned short)(r >> 16);
}

__device__ inline void gload_lds16(const void* g, void* l) {
    __builtin_amdgcn_global_load_lds(
        (const __attribute__((address_space(1))) void*)g,
        (__attribute__((address_space(3))) void*)l, 16, 0, 0);
}

// ---------------- fp32 -> bf16 cast for x and W in one launch ----------------
__global__ void cast2_bf16_kernel(const float* __restrict__ sa,
                                  unsigned short* __restrict__ da, int n8a,
                                  const float* __restrict__ sb,
                                  unsigned short* __restrict__ db, int n8b) {
    int i = blockIdx.x * blockDim.x + threadIdx.x;
    const float* s;
    unsigned short* d;
    size_t j;
    if (i < n8a) { s = sa; d = da; j = (size_t)i; }
    else if (i < n8a + n8b) { s = sb; d = db; j = (size_t)(i - n8a); }
    else return;
    const float4* s4 = (const float4*)s;
    float4 a = s4[2 * j];
    float4 b = s4[2 * j + 1];
    u16x8 o;
    o[0] = f2bf(a.x); o[1] = f2bf(a.y); o[2] = f2bf(a.z); o[3] = f2bf(a.w);
    o[4] = f2bf(b.x); o[5] = f2bf(b.y); o[6] = f2bf(b.z); o[7] = f2bf(b.w);
    *(u16x8*)(d + 8 * j) = o;
}

// ---------- At[s][m*16+r][d] = lora_A[m][s][d][r]  (bf16) --------------------
__global__ void prep_A_kernel(const float* __restrict__ A,
                              unsigned short* __restrict__ At) {
    int idx = blockIdx.x * 256 + threadIdx.x;     // NSEG*32*DIN total
    int d   = idx & (DIN - 1);
    int smr = idx >> 12;
    int s   = smr >> 5, mr = smr & 31;
    int m   = mr >> 4,  r  = mr & 15;
    float v = A[(((size_t)(m * NSEG + s) * DIN) + d) * RANK + r];
    At[idx] = f2bf(v);
}

// ---------- Bt[s][o][m*16+r] = lora_B[m][s][r][o]  (bf16) --------------------
__global__ void prep_B_kernel(const float* __restrict__ B,
                              unsigned short* __restrict__ Bt) {
    int o  = blockIdx.x * 256 + threadIdx.x;      // NSEG*DOUT total
    int s  = o >> 12;
    int oc = o & (DOUT - 1);
    unsigned short tmp[32];
    for (int m = 0; m < NMOD; ++m)
        for (int r = 0; r < RANK; ++r)
            tmp[m * 16 + r] =
                f2bf(B[(((size_t)(m * NSEG + s) * RANK) + r) * DOUT + oc]);
    for (int k = 0; k < 4; ++k) {
        u16x8 v;
        for (int j = 0; j < 8; ++j) v[j] = tmp[k * 8 + j];
        *(u16x8*)(Bt + (size_t)o * 32 + k * 8) = v;
    }
}

// ---------- u partials: Pu[ky][t][mr] = sum_{k in split} x[t,k]*At[s(t)][mr][k]
__global__ __launch_bounds__(64) void u_gemm_kernel(
    const unsigned short* __restrict__ xb, const unsigned short* __restrict__ At,
    const int* __restrict__ cu, float* __restrict__ Pu) {
    int tile = blockIdx.x;          // 0..255
    int ky   = blockIdx.y;          // 0..3
    int lane = threadIdx.x;
    int l15  = lane & 15, lk = lane >> 4;
    int t0   = tile * 32;
    f32x4 acc[2][2] = {};
    bf16x8 zero = {};
    for (int s = 0; s < NSEG; ++s) {
        int lo = cu[s], hi = cu[s + 1];
        if (hi <= t0 || lo >= t0 + 32) continue;
        const unsigned short* atb = At + (size_t)(s * 32) * DIN;
        for (int kt = 0; kt < 32; ++kt) {
            int k0 = ky * 1024 + kt * 32 + lk * 8;
            bf16x8 a[2], b[2];
            for (int mi = 0; mi < 2; ++mi) {
                int row = t0 + mi * 16 + l15;
                bf16x8 av = *(const bf16x8*)(xb + (size_t)row * DIN + k0);
                a[mi] = (row >= lo && row < hi) ? av : zero;
            }
            for (int ni = 0; ni < 2; ++ni) {
                int mr = ni * 16 + l15;
                b[ni] = *(const bf16x8*)(atb + (size_t)mr * DIN + k0);
            }
            for (int mi = 0; mi < 2; ++mi)
                for (int ni = 0; ni < 2; ++ni)
                    acc[mi][ni] = __builtin_amdgcn_mfma_f32_16x16x32_bf16(
                        a[mi], b[ni], acc[mi][ni], 0, 0, 0);
        }
    }
    for (int mi = 0; mi < 2; ++mi)
        for (int ni = 0; ni < 2; ++ni)
            for (int j = 0; j < 4; ++j) {
                int t  = t0 + mi * 16 + lk * 4 + j;
                int mr = ni * 16 + l15;
                Pu[((size_t)ky * T_TOK + t) * 32 + mr] = acc[mi][ni][j];
            }
}

// ---------- reduce 4 K-split partials -> ub bf16 [T][32] ---------------------
__global__ void reduce_u_kernel(const float* __restrict__ Pu,
                                unsigned short* __restrict__ ub) {
    int idx = blockIdx.x * 256 + threadIdx.x;   // T_TOK*32
    const size_t STRIDE = (size_t)T_TOK * 32;
    float s = Pu[idx] + Pu[idx + STRIDE] + Pu[idx + 2 * STRIDE] + Pu[idx + 3 * STRIDE];
    ub[idx] = f2bf(s);
}

// ============================================================================
// Main GEMM — 2-blocks/CU with 256x256 tile. BK=32, 8 waves (2Mx4N), LDS 64KiB
// double-buffer (A[256][32]+B[256][32] = 32 KiB/slot). ONE barrier per K-tile:
//   { ds_read 12 frags(t, slot s) ; stage 4 gloads (t+1 -> slot s^1) ;
//     setprio(1) 32 MFMA setprio(0) ; vmcnt(0) ; s_barrier }
//
// R13 fix vs R12: __launch_bounds__(512, 2) — NOT (512,4). (512,4) capped
// VGPR at 128/wave; the kernel needs ~176 live regs -> accumulator spilled
// to scratch (R12: VGPR_Count 64, WRITE_SIZE 9.75 GB, 3311 us). With cap 256
// the allocator lands at ~128 (R2-R8 precedent), and the HW occupancy rule
// (waves halve at 64/128/256 VGPR) still gives 4 waves/SIMD = 16 waves/CU =
// 2 blocks co-resident given 64 KiB LDS — the co-residency R12's occupancy
// counter (45%) already demonstrated, now without spills.
//
// dbuf audit: iter t reads slot t&1; stages into slot (t&1)^1, whose readers
// (tile t-1) completed before end-of-(t-1) barrier. vmcnt(0)+barrier at end
// of t makes tile t+1 visible. Stage->use distance ~1 K-tile >> HBM latency.
// Swizzle (64B rows, verified 0-conflict R9/R10): slot16 ^= (row>>1)&3 on
// SOURCE of global_load_lds (linear dest) and on ds_read address.
// XCD col-panel mapping: xcd=bid&7 owns col-panels {2*xcd, 2*xcd+1}.
// ============================================================================

__device__ __forceinline__ bf16x8 fragA(const char* mat, int row, int lk) {
    int rb = (row << 6) + ((lk ^ ((row >> 1) & 3)) << 4);
    return *(const bf16x8*)(mat + rb);
}

// stage 8 KiB round (512 threads x 16 B): rows TB>>6, pre-swizzled source
#define STAGE_R(GB_, LD_, TB_, K0_)                                           \
  { int tb = (TB_);                                                            \
    int lrow = tb >> 6;                                                        \
    int cb = (tb & 63) ^ (((lrow >> 1) & 3) << 4);                             \
    gload_lds16((GB_) + (size_t)lrow * DIN + (K0_) + (cb >> 1), (LD_) + tb); }

#define BODY(T_, S_, STG_, VM_, BAR_)                                          \
  {                                                                            \
    const char* cA = lds + (S_) * 32768;                                       \
    const char* cB = cA + 16384;                                               \
    char* sA = lds + (1 - (S_)) * 32768;                                       \
    char* sB = sA + 16384;                                                     \
    const int k0n = ((T_) + 1) * 32;                                           \
    bf16x8 af[8], bf[4];                                                       \
    for (int n = 0; n < 4; ++n) bf[n] = fragA(cB, wcol + n*16 + l15, lk);      \
    for (int m = 0; m < 8; ++m) af[m] = fragA(cA, wrow + m*16 + l15, lk);      \
    if (STG_) {                                                                \
        STAGE_R(xrow, sA, tid*16, k0n);                                        \
        STAGE_R(xrow, sA, 8192 + tid*16, k0n);                                 \
        STAGE_R(wrow_g, sB, tid*16, k0n);                                      \
        STAGE_R(wrow_g, sB, 8192 + tid*16, k0n);                               \
    }                                                                          \
    __builtin_amdgcn_s_setprio(1);                                             \
    for (int m = 0; m < 8; ++m)                                                \
        for (int n = 0; n < 4; ++n)                                            \
            acc[m][n] = __builtin_amdgcn_mfma_f32_16x16x32_bf16(               \
                af[m], bf[n], acc[m][n], 0, 0, 0);                             \
    __builtin_amdgcn_s_setprio(0);                                             \
    if ((VM_) >= 0) asm volatile("s_waitcnt vmcnt(0)" ::: "memory");           \
    if (BAR_) __builtin_amdgcn_s_barrier();                                    \
  }

__global__ __launch_bounds__(512, 2) void main_gemm_kernel(
    const unsigned short* __restrict__ xb, const unsigned short* __restrict__ wb,
    const unsigned short* __restrict__ ub, const unsigned short* __restrict__ bt,
    const float* __restrict__ bias, const int* __restrict__ cu,
    float* __restrict__ out) {
    __shared__ __attribute__((aligned(1024))) char lds[65536];  // 2 x 32 KiB
    int tid  = threadIdx.x;
    int w    = tid >> 6, lane = tid & 63;
    int l15  = lane & 15, lk = lane >> 4;
    int wrow = (w >> 2) * 128;          // wave M-offset in tile
    int wcol = (w & 3) * 64;            // wave N-offset in tile
    // XCD col-panel mapping: xcd owns col-panels {2*xcd, 2*xcd+1}
    int xcd   = blockIdx.x & 7;
    int local = blockIdx.x >> 3;        // 0..63
    int colp  = xcd * 2 + (local >> 5); // 0..15
    int rowp  = local & 31;             // 0..31
    int row0 = rowp * 256, col0 = colp * 256;

    const unsigned short* xrow   = xb + (size_t)row0 * DIN;
    const unsigned short* wrow_g = wb + (size_t)col0 * DIN;

    f32x4 acc[8][4] = {};

    // prologue: stage tile 0 into slot 0
    STAGE_R(xrow, lds, tid*16, 0);
    STAGE_R(xrow, lds, 8192 + tid*16, 0);
    STAGE_R(wrow_g, lds + 16384, tid*16, 0);
    STAGE_R(wrow_g, lds + 16384, 8192 + tid*16, 0);
    asm volatile("s_waitcnt vmcnt(0)" ::: "memory");
    __builtin_amdgcn_s_barrier();

    // main loop: 128 K-tiles of 32; unroll x2 for static dbuf slots
    #pragma unroll 1
    for (int t = 0; t < 126; t += 2) {
        BODY(t,     0, 1, 0, 1);
        BODY(t + 1, 1, 1, 0, 1);
    }
    BODY(126, 0, 1, 0, 1);   // stages tile 127 (stage distance = 1)
    BODY(127, 1, 0, -1, 0);

    // fused LoRA up-projection: one extra K=32 MFMA step per overlapping segment
    bf16x8 zero = {};
    for (int s = 0; s < NSEG; ++s) {
        int lo = cu[s], hi = cu[s + 1];
        if (hi <= row0 || lo >= row0 + 256) continue;
        bf16x8 au[8], bu[4];
        for (int m = 0; m < 8; ++m) {
            int row = row0 + wrow + m * 16 + l15;
            bf16x8 v = *(const bf16x8*)(ub + (size_t)row * 32 + lk * 8);
            au[m] = (row >= lo && row < hi) ? v : zero;
        }
        for (int n = 0; n < 4; ++n) {
            int col = col0 + wcol + n * 16 + l15;
            bu[n] = *(const bf16x8*)(bt + ((size_t)s * DOUT + col) * 32 + lk * 8);
        }
        for (int m = 0; m < 8; ++m)
            for (int n = 0; n < 4; ++n)
                acc[m][n] = __builtin_amdgcn_mfma_f32_16x16x32_bf16(
                    au[m], bu[n], acc[m][n], 0, 0, 0);
    }

    // epilogue: + bias, fp32 store
    float bv[4];
    for (int n = 0; n < 4; ++n) bv[n] = bias[col0 + wcol + n * 16 + l15];
    for (int m = 0; m < 8; ++m) {
        int rbase = row0 + wrow + m * 16 + lk * 4;
        for (int n = 0; n < 4; ++n) {
            int col = col0 + wcol + n * 16 + l15;
            for (int jj = 0; jj < 4; ++jj)
                out[(size_t)(rbase + jj) * DOUT + col] = acc[m][n][jj] + bv[n];
        }
    }
}

extern "C" void kernel_launch(void* const* d_in, const int* in_sizes, int n_in,
                              void* d_out, int out_size, void* d_ws, size_t ws_size,
                              hipStream_t stream) {
    const float* x  = (const float*)d_in[0];
    const float* W  = (const float*)d_in[1];
    const float* b  = (const float*)d_in[2];
    const float* lA = (const float*)d_in[3];
    const float* lB = (const float*)d_in[4];
    const int*   cu = (const int*)d_in[5];
    float* out = (float*)d_out;

    char* ws = (char*)d_ws;
    unsigned short* xb = (unsigned short*)(ws);                    // 64 MiB
    unsigned short* wb = (unsigned short*)(ws + 67108864);         // 32 MiB
    unsigned short* At = (unsigned short*)(ws + 100663296);        // 2 MiB
    unsigned short* Bt = (unsigned short*)(ws + 102760448);        // 2 MiB
    float*          Pu = (float*)(ws + 104857600);                 // 4 MiB
    unsigned short* ub = (unsigned short*)(ws + 109051904);        // 0.5 MiB

    const int n8x = T_TOK * DIN / 8, n8w = DOUT * DIN / 8;
    cast2_bf16_kernel<<<(n8x + n8w) / 256, 256, 0, stream>>>(x, xb, n8x, W, wb, n8w);
    prep_A_kernel<<<(NSEG * 32 * DIN) / 256, 256, 0, stream>>>(lA, At);
    prep_B_kernel<<<(NSEG * DOUT) / 256, 256, 0, stream>>>(lB, Bt);
    dim3 ug(T_TOK / 32, 4);
    u_gemm_kernel<<<ug, 64, 0, stream>>>(xb, At, cu, Pu);
    reduce_u_kernel<<<(T_TOK * 32) / 256, 256, 0, stream>>>(Pu, ub);
    dim3 mg(32 * 16);   // 512 tiles of 256x256
    main_gemm_kernel<<<mg, 512, 0, stream>>>(xb, wb, ub, Bt, b, cu, out);
}